// Round 2
// baseline (2118.225 us; speedup 1.0000x reference)
//
#include <hip/hip_runtime.h>
#include <cmath>

#define HEAD_DIM 64
#define N_HEADS  25
#define N_KV     5
#define WINDOW   1024
#define N_META   128
#define B_       2
#define T_       2048
#define QB       64   // queries per block
// T_/QB = 32 query-tiles

// ---------------- Kernel 1: RMSNorm + RoPE for K, into ws ----------------
// one 64-lane wave per (b, t, kv-head) row; out layout [B][N_KV][T][64]
__global__ __launch_bounds__(256) void prep_k_kernel(
    const float* __restrict__ k_in, const float* __restrict__ k_w,
    const int* __restrict__ pos_ids, float* __restrict__ k_out)
{
  int gw   = (blockIdx.x * blockDim.x + threadIdx.x) >> 6;
  int lane = threadIdx.x & 63;
  if (gw >= B_ * T_ * N_KV) return;
  int kvh = gw % N_KV;
  int bt  = gw / N_KV;

  float x = k_in[(size_t)bt * (N_KV * HEAD_DIM) + kvh * HEAD_DIM + lane];
  float ss = x * x;
  #pragma unroll
  for (int off = 32; off; off >>= 1) ss += __shfl_xor(ss, off);
  float y = k_w[lane] * x * rsqrtf(ss * (1.f / 64.f) + 1e-6f);

  int   pos = pos_ids[bt];
  float ang = (float)pos * powf(10000.f, -(float)(lane & 31) * (1.f / 32.f));
  float c, s;
  sincosf(ang, &s, &c);              // sincosf(x, sin*, cos*) — order matters!
  float part = __shfl_xor(y, 32);
  float r = (lane < 32) ? (y * c - part * s) : (y * c + part * s);

  int b = bt / T_, t = bt % T_;
  k_out[((size_t)(b * N_KV + kvh) * T_ + t) * HEAD_DIM + lane] = r;
}

// ---------------- Kernel 2: fused SWA+meta attention ----------------
// block = 256 threads (4 waves); block owns (b, h, 64-query tile);
// wave w owns queries [w*16, w*16+16).
__global__ __launch_bounds__(256) void attn_kernel(
    const float* __restrict__ q_in, const float* __restrict__ q_w,
    const int* __restrict__ pos_ids, const float* __restrict__ kp,
    const float* __restrict__ v_in, float* __restrict__ out)
{
  const int blk  = blockIdx.x;
  const int qb   = (blk & 31) * QB;            // T_/QB == 32
  const int h    = (blk >> 5) % N_HEADS;
  const int b    = blk / (32 * N_HEADS);
  const int kvh  = h / (N_HEADS / N_KV);       // h / 5
  const int tid  = threadIdx.x;
  const int wid  = tid >> 6;
  const int lane = tid & 63;

  __shared__ float Qs[QB][HEAD_DIM];           // broadcast reads -> no pad needed
  __shared__ float Ks[64][HEAD_DIM + 1];       // +1 pad: 2-way aliasing only (free)
  __shared__ float Vs[64][HEAD_DIM + 1];

  // ---- stage Q block: RMSNorm + RoPE, scale 1/sqrt(64)=0.125 folded in ----
  for (int r = wid; r < QB; r += 4) {
    int t = qb + r;
    float x = q_in[((size_t)(b * T_ + t)) * (N_HEADS * HEAD_DIM) + h * HEAD_DIM + lane];
    float ss = x * x;
    #pragma unroll
    for (int off = 32; off; off >>= 1) ss += __shfl_xor(ss, off);
    float y = q_w[lane] * x * rsqrtf(ss * (1.f / 64.f) + 1e-6f);
    int   pos = pos_ids[b * T_ + t];
    float ang = (float)pos * powf(10000.f, -(float)(lane & 31) * (1.f / 32.f));
    float c, s;
    sincosf(ang, &s, &c);            // sincosf(x, sin*, cos*) — order matters!
    float part = __shfl_xor(y, 32);
    float rv = (lane < 32) ? (y * c - part * s) : (y * c + part * s);
    Qs[r][lane] = rv * 0.125f;
  }

  float m[16], l[16], o[16];
  #pragma unroll
  for (int i = 0; i < 16; ++i) { m[i] = -INFINITY; l[i] = 0.f; o[i] = 0.f; }

  const int qmax  = qb + QB - 1;
  const int qrow0 = wid * 16;

  for (int k0 = 0; k0 <= qmax; k0 += 64) {
    // tile fully masked for every query in block? (past meta, before window)
    if (k0 >= N_META && (k0 + 63) < qb - (WINDOW - 1)) continue;

    __syncthreads();   // previous tile fully consumed (also covers Qs staging)
    for (int idx = tid; idx < 64 * HEAD_DIM; idx += 256) {
      int r = idx >> 6, c = idx & 63;
      Ks[r][c] = kp[((size_t)(b * N_KV + kvh) * T_ + (k0 + r)) * HEAD_DIM + c];
      Vs[r][c] = v_in[((size_t)(b * T_ + (k0 + r))) * (N_KV * HEAD_DIM) + kvh * HEAD_DIM + c];
    }
    __syncthreads();

    // ---- scoring: lane owns key (k0+lane); 16 queries per wave ----
    float p[16];
    #pragma unroll
    for (int i = 0; i < 16; ++i) p[i] = 0.f;
    for (int d = 0; d < HEAD_DIM; ++d) {
      float kv = Ks[lane][d];
      #pragma unroll
      for (int qq = 0; qq < 16; ++qq)
        p[qq] = fmaf(Qs[qrow0 + qq][d], kv, p[qq]);
    }

    const int kabs = k0 + lane;
    #pragma unroll
    for (int qq = 0; qq < 16; ++qq) {
      int  q  = qb + qrow0 + qq;
      bool ok = (kabs <= q) && ((kabs >= q - (WINDOW - 1)) || (kabs < N_META));
      float s = ok ? p[qq] : -INFINITY;
      float Mt = s;
      #pragma unroll
      for (int off = 32; off; off >>= 1) Mt = fmaxf(Mt, __shfl_xor(Mt, off));
      float mn = fmaxf(m[qq], Mt);          // finite after (and during) tile 0
      float pi = __expf(s - mn);            // masked -> exp(-inf) = 0
      float Pt = pi;
      #pragma unroll
      for (int off = 32; off; off >>= 1) Pt += __shfl_xor(Pt, off);
      float sc = __expf(m[qq] - mn);        // m=-inf at tile0 -> 0, ok
      l[qq] = l[qq] * sc + Pt;
      o[qq] *= sc;
      m[qq] = mn;
      p[qq] = pi;
    }

    // ---- PV: lane owns output dim; broadcast p_i from lane i ----
    for (int i = 0; i < 64; ++i) {
      float v = Vs[i][lane];
      #pragma unroll
      for (int qq = 0; qq < 16; ++qq)
        o[qq] = fmaf(__shfl(p[qq], i), v, o[qq]);
    }
  }

  #pragma unroll
  for (int qq = 0; qq < 16; ++qq) {
    int t = qb + qrow0 + qq;
    out[((size_t)(b * T_ + t)) * (N_HEADS * HEAD_DIM) + h * HEAD_DIM + lane] = o[qq] / l[qq];
  }
}

extern "C" void kernel_launch(void* const* d_in, const int* in_sizes, int n_in,
                              void* d_out, int out_size, void* d_ws, size_t ws_size,
                              hipStream_t stream) {
  const float* q   = (const float*)d_in[0];
  const float* k   = (const float*)d_in[1];
  const float* v   = (const float*)d_in[2];
  const float* qw  = (const float*)d_in[3];
  const float* kw  = (const float*)d_in[4];
  const int*   pos = (const int*)d_in[5];
  float* kp   = (float*)d_ws;     // B*N_KV*T*64 floats = 5.24 MB
  float* outp = (float*)d_out;

  // prep K: B*T*N_KV waves = 20480 waves -> 5120 blocks of 256
  prep_k_kernel<<<5120, 256, 0, stream>>>(k, kw, pos, kp);
  // attention: B * N_HEADS * (T/QB) = 2*25*32 = 1600 blocks
  attn_kernel<<<1600, 256, 0, stream>>>(q, qw, pos, kp, v, outp);
}

// Round 3
// 147.790 us; speedup vs baseline: 14.3327x; 14.3327x over previous
//
#include <hip/hip_runtime.h>
#include <cmath>

typedef float  f32x4  __attribute__((ext_vector_type(4)));
typedef __bf16 bf16x8 __attribute__((ext_vector_type(8)));
typedef unsigned int u32x4 __attribute__((ext_vector_type(4)));
typedef unsigned int   u32;
typedef unsigned short u16;

#define HEAD_DIM 64
#define N_HEADS  25
#define N_KV     5
#define WINDOW   1024
#define N_META   128
#define B_       2
#define T_       2048
#define QB       64

static __device__ __forceinline__ u16 bf16_bits(float f) {
  __bf16 h = (__bf16)f;
  return __builtin_bit_cast(u16, h);
}

// ---------------- Kernel 1: RMSNorm + RoPE for K -> bf16 packed ws ----------------
// one 64-lane wave per (b, t, kv-head) row; out: u32 rows of 32 (64 bf16), [B][N_KV][T][32]
__global__ __launch_bounds__(256) void prep_k_kernel(
    const float* __restrict__ k_in, const float* __restrict__ k_w,
    const int* __restrict__ pos_ids, u32* __restrict__ k_out)
{
  int gw   = (blockIdx.x * blockDim.x + threadIdx.x) >> 6;
  int lane = threadIdx.x & 63;
  if (gw >= B_ * T_ * N_KV) return;
  int kvh = gw % N_KV;
  int bt  = gw / N_KV;

  float x = k_in[(size_t)bt * (N_KV * HEAD_DIM) + kvh * HEAD_DIM + lane];
  float ss = x * x;
  #pragma unroll
  for (int off = 32; off; off >>= 1) ss += __shfl_xor(ss, off);
  float y = k_w[lane] * x * rsqrtf(ss * (1.f / 64.f) + 1e-6f);

  int   pos = pos_ids[bt];
  float ang = (float)pos * powf(10000.f, -(float)(lane & 31) * (1.f / 32.f));
  float c, s;
  sincosf(ang, &s, &c);
  float part = __shfl_xor(y, 32);
  float r = (lane < 32) ? (y * c - part * s) : (y * c + part * s);

  u16 mybits = bf16_bits(r);
  u32 pb = (u32)(u16)__shfl_xor((int)mybits, 1);
  u32 w  = (pb << 16) | mybits;          // even lane: (lo=d even, hi=d odd)
  int b = bt / T_, t = bt % T_;
  if (!(lane & 1))
    k_out[((size_t)(b * N_KV + kvh) * T_ + t) * 32 + (lane >> 1)] = w;
}

// ---------------- Kernel 1b: V fp32 -> bf16 packed (same layout as input) ----------------
__global__ __launch_bounds__(256) void prep_v_kernel(
    const float* __restrict__ v_in, u32* __restrict__ v_out)
{
  int idx = blockIdx.x * blockDim.x + threadIdx.x;   // one per 4 floats
  const int total = B_ * T_ * N_KV * HEAD_DIM / 4;   // 327680
  if (idx >= total) return;
  const float4 v = ((const float4*)v_in)[idx];
  u32 w0 = ((u32)bf16_bits(v.y) << 16) | bf16_bits(v.x);
  u32 w1 = ((u32)bf16_bits(v.w) << 16) | bf16_bits(v.z);
  v_out[2 * idx]     = w0;
  v_out[2 * idx + 1] = w1;
}

// ---------------- Kernel 2: fused MFMA flash attention ----------------
// block = 256 threads (4 waves); block owns (b, h, 64-query tile); wave owns 16 queries.
__global__ __launch_bounds__(256) void attn_kernel(
    const float* __restrict__ q_in, const float* __restrict__ q_w,
    const int* __restrict__ pos_ids,
    const u32* __restrict__ kp, const u16* __restrict__ vp,
    float* __restrict__ out)
{
  const int blk = blockIdx.x;
  const int qt  = blk & 31;
  const int h   = (blk >> 5) % N_HEADS;
  const int b   = blk / (32 * N_HEADS);
  const int qb  = qt * QB;
  const int kvh = h / (N_HEADS / N_KV);
  const int tid = threadIdx.x, wid = tid >> 6, lane = tid & 63;
  const int l15 = lane & 15, g = lane >> 4;
  const int qrow0 = wid * 16;

  __shared__ u32 Ks32[64][36];       // K tile bf16: row=key (144B stride, 16B pad)
  __shared__ u32 Vt32[64][32];       // V^T tile bf16: row=d, cols=key-pairs, seg-XOR swizzled
  __shared__ u32 Pq32[4][16][36];    // per-wave: Q rows (init) then P rows (main loop)

  // ---- Q staging: wave computes its own 16 rows (RMSNorm+RoPE, *0.125), bf16-packed ----
  {
    const float base = powf(10000.f, -(float)(lane & 31) * (1.f / 32.f));
    for (int r = 0; r < 16; ++r) {
      int t = qb + qrow0 + r;
      float x = q_in[((size_t)(b * T_ + t)) * (N_HEADS * HEAD_DIM) + h * HEAD_DIM + lane];
      float ss = x * x;
      #pragma unroll
      for (int off = 32; off; off >>= 1) ss += __shfl_xor(ss, off);
      float y = q_w[lane] * x * rsqrtf(ss * (1.f / 64.f) + 1e-6f);
      float ang = (float)pos_ids[b * T_ + t] * base;
      float c, s;
      sincosf(ang, &s, &c);
      float part = __shfl_xor(y, 32);
      float rv = ((lane < 32) ? (y * c - part * s) : (y * c + part * s)) * 0.125f;
      u16 mybits = bf16_bits(rv);
      u32 pb = (u32)(u16)__shfl_xor((int)mybits, 1);
      u32 w  = (pb << 16) | mybits;
      if (!(lane & 1)) Pq32[wid][r][lane >> 1] = w;
    }
  }

  // Q fragments (B operand): lane holds Q[q=l15][d = 32*ks + 8*g + j]
  bf16x8 qf[2];
  #pragma unroll
  for (int ks = 0; ks < 2; ++ks)
    qf[ks] = *(const bf16x8*)&Pq32[wid][l15][16 * ks + 4 * g];

  float m_reg = -INFINITY, l_reg = 0.f;
  f32x4 acc_o[4];
  #pragma unroll
  for (int mt = 0; mt < 4; ++mt) acc_o[mt] = (f32x4)(0.f);

  const int q_abs = qb + qrow0 + l15;
  const int qmax  = qb + QB - 1;

  for (int k0 = 0; k0 <= qmax; k0 += 64) {
    if (k0 >= N_META && (k0 + 63) < qb - (WINDOW - 1)) continue;  // fully-masked tile

    __syncthreads();   // previous tile fully consumed
    // ---- stage K tile (bf16 rows, 16B segs) ----
    #pragma unroll
    for (int it = 0; it < 2; ++it) {
      int sidx = tid + it * 256;
      int kr = sidx >> 3, sg = sidx & 7;
      u32x4 d4 = *(const u32x4*)&kp[(((size_t)(b * N_KV + kvh)) * T_ + (k0 + kr)) * 32 + sg * 4];
      *(u32x4*)&Ks32[kr][sg * 4] = d4;
    }
    // ---- stage V transposed: Vt[d][key-pair], seg-XOR swizzle for b128 reads ----
    #pragma unroll
    for (int it = 0; it < 8; ++it) {
      int idx = tid + it * 256;
      int r2 = idx >> 6;            // key pair index 0..31
      int c  = idx & 63;            // d
      size_t vbase = ((size_t)(b * T_ + k0 + 2 * r2)) * (N_KV * HEAD_DIM) + kvh * HEAD_DIM + c;
      u32 lo = vp[vbase];
      u32 hi = vp[vbase + (size_t)(N_KV * HEAD_DIM)];
      Vt32[c][((((r2 >> 2) ^ (c & 7))) << 2) | (r2 & 3)] = (hi << 16) | lo;
    }
    __syncthreads();

    // ---- K fragments (A operand): lane holds K[key = 16mt + l15][d = 32ks + 8g + j] ----
    bf16x8 kf[4][2];
    #pragma unroll
    for (int mt = 0; mt < 4; ++mt)
      #pragma unroll
      for (int ks = 0; ks < 2; ++ks)
        kf[mt][ks] = *(const bf16x8*)&Ks32[16 * mt + l15][16 * ks + 4 * g];

    // ---- S^T = K · Q^T : C[key][q], col=l15=q, row=4g+reg=key-within-mt ----
    f32x4 accs[4];
    #pragma unroll
    for (int mt = 0; mt < 4; ++mt) {
      f32x4 z = {0.f, 0.f, 0.f, 0.f};
      z = __builtin_amdgcn_mfma_f32_16x16x32_bf16(kf[mt][0], qf[0], z, 0, 0, 0);
      z = __builtin_amdgcn_mfma_f32_16x16x32_bf16(kf[mt][1], qf[1], z, 0, 0, 0);
      accs[mt] = z;
    }

    // ---- mask + online softmax (lane owns query l15; g-groups replicate) ----
    float pv[4][4];
    float tmax = -INFINITY;
    #pragma unroll
    for (int mt = 0; mt < 4; ++mt)
      #pragma unroll
      for (int rg = 0; rg < 4; ++rg) {
        int key = k0 + 16 * mt + 4 * g + rg;
        bool ok = (key <= q_abs) && ((key >= q_abs - (WINDOW - 1)) || (key < N_META));
        float sv = ok ? accs[mt][rg] : -INFINITY;
        pv[mt][rg] = sv;
        tmax = fmaxf(tmax, sv);
      }
    tmax = fmaxf(tmax, __shfl_xor(tmax, 16));
    tmax = fmaxf(tmax, __shfl_xor(tmax, 32));
    float mn  = fmaxf(m_reg, tmax);            // finite from tile 0 on (meta keys)
    float scl = __expf(m_reg - mn);
    m_reg = mn;
    float rsum = 0.f;
    #pragma unroll
    for (int mt = 0; mt < 4; ++mt)
      #pragma unroll
      for (int rg = 0; rg < 4; ++rg) {
        float pi = __expf(pv[mt][rg] - mn);    // -inf -> 0
        pv[mt][rg] = pi;
        rsum += pi;
      }
    rsum += __shfl_xor(rsum, 16);
    rsum += __shfl_xor(rsum, 32);
    l_reg = l_reg * scl + rsum;

    // ---- pack P -> wave-private LDS: P[q=l15][key-pair col], col j holds keys (2j,2j+1) ----
    #pragma unroll
    for (int mt = 0; mt < 4; ++mt)
      #pragma unroll
      for (int c2 = 0; c2 < 2; ++c2) {
        u32 w = ((u32)bf16_bits(pv[mt][2 * c2 + 1]) << 16) | bf16_bits(pv[mt][2 * c2]);
        Pq32[wid][l15][8 * mt + 2 * g + c2] = w;
      }

    // ---- rescale O accumulator (its rows are q' = 4g + reg) ----
    float scl4[4];
    #pragma unroll
    for (int rg = 0; rg < 4; ++rg) scl4[rg] = __shfl(scl, 4 * g + rg);
    #pragma unroll
    for (int mt2 = 0; mt2 < 4; ++mt2)
      #pragma unroll
      for (int rg = 0; rg < 4; ++rg) acc_o[mt2][rg] *= scl4[rg];

    // ---- O += P · V : A=P[q][k-run], B=V[k][d] (from swizzled Vt) ----
    #pragma unroll
    for (int ks2 = 0; ks2 < 2; ++ks2) {
      bf16x8 af = *(const bf16x8*)&Pq32[wid][l15][16 * ks2 + 4 * g];
      #pragma unroll
      for (int mt2 = 0; mt2 < 4; ++mt2) {
        bf16x8 vf = *(const bf16x8*)&Vt32[16 * mt2 + l15][((g + 4 * ks2) ^ (l15 & 7)) << 2];
        acc_o[mt2] = __builtin_amdgcn_mfma_f32_16x16x32_bf16(af, vf, acc_o[mt2], 0, 0, 0);
      }
    }
  }

  // ---- epilogue: O[q'][d] / l(q'); acc rows are q' = 4g + rg ----
  float l4[4];
  #pragma unroll
  for (int rg = 0; rg < 4; ++rg) l4[rg] = __shfl(l_reg, 4 * g + rg);
  #pragma unroll
  for (int mt2 = 0; mt2 < 4; ++mt2)
    #pragma unroll
    for (int rg = 0; rg < 4; ++rg) {
      int t = qb + qrow0 + 4 * g + rg;
      out[((size_t)(b * T_ + t)) * (N_HEADS * HEAD_DIM) + h * HEAD_DIM + 16 * mt2 + l15] =
          acc_o[mt2][rg] / l4[rg];
    }
}

extern "C" void kernel_launch(void* const* d_in, const int* in_sizes, int n_in,
                              void* d_out, int out_size, void* d_ws, size_t ws_size,
                              hipStream_t stream) {
  const float* q   = (const float*)d_in[0];
  const float* k   = (const float*)d_in[1];
  const float* v   = (const float*)d_in[2];
  const float* qw  = (const float*)d_in[3];
  const float* kw  = (const float*)d_in[4];
  const int*   pos = (const int*)d_in[5];

  u32* kp = (u32*)d_ws;                         // B*N_KV*T*32 u32 = 2.62 MB
  u32* vp = kp + (size_t)B_ * N_KV * T_ * 32;   // 2.62 MB
  float* outp = (float*)d_out;

  prep_k_kernel<<<5120, 256, 0, stream>>>(k, kw, pos, kp);
  prep_v_kernel<<<1280, 256, 0, stream>>>(v, vp);
  attn_kernel<<<1600, 256, 0, stream>>>(q, qw, pos, kp, (const u16*)vp, outp);
}

// Round 4
// 132.546 us; speedup vs baseline: 15.9811x; 1.1150x over previous
//
#include <hip/hip_runtime.h>
#include <cmath>

typedef float  f32x4  __attribute__((ext_vector_type(4)));
typedef __bf16 bf16x8 __attribute__((ext_vector_type(8)));
typedef unsigned int   u32;
typedef unsigned short u16;

#define HEAD_DIM 64
#define N_HEADS  25
#define N_KV     5
#define WINDOW   1024
#define N_META   128
#define B_       2
#define T_       2048
#define QB       64
#define NTILES   (T_ / 64)          // 32 k-tiles per (b,kvh)
#define TILE_U32 2048               // 64 rows x 32 u32 (8 KB)

static __device__ __forceinline__ u16 bf16_bits(float f) {
  __bf16 h = (__bf16)f;
  return __builtin_bit_cast(u16, h);
}

static __device__ __forceinline__ void gload16(const u32* g, u32* l) {
  __builtin_amdgcn_global_load_lds((const __attribute__((address_space(1))) u32*)g,
                                   (__attribute__((address_space(3))) u32*)l, 16, 0, 0);
}

// ---------------- Kernel 1: K RMSNorm+RoPE -> bf16, tile-blocked + XOR-pre-swizzled ----
// ws layout: [b][kvh][tile][key_local(64)][seg_phys(8) of 16B]; seg_phys = seg_log ^ (kl&7)
__global__ __launch_bounds__(256) void prep_k_kernel(
    const float* __restrict__ k_in, const float* __restrict__ k_w,
    const int* __restrict__ pos_ids, u32* __restrict__ k_ws)
{
  int gw   = (blockIdx.x * blockDim.x + threadIdx.x) >> 6;
  int lane = threadIdx.x & 63;
  if (gw >= B_ * T_ * N_KV) return;
  int kvh = gw % N_KV;
  int bt  = gw / N_KV;

  float x = k_in[(size_t)bt * (N_KV * HEAD_DIM) + kvh * HEAD_DIM + lane];
  float ss = x * x;
  #pragma unroll
  for (int off = 32; off; off >>= 1) ss += __shfl_xor(ss, off);
  float y = k_w[lane] * x * rsqrtf(ss * (1.f / 64.f) + 1e-6f);

  int   pos = pos_ids[bt];
  float ang = (float)pos * powf(10000.f, -(float)(lane & 31) * (1.f / 32.f));
  float c, s;
  sincosf(ang, &s, &c);            // sincosf(x, sin*, cos*)
  float part = __shfl_xor(y, 32);
  float r = (lane < 32) ? (y * c - part * s) : (y * c + part * s);

  u16 mybits = bf16_bits(r);
  u32 pb = (u32)(u16)__shfl_xor((int)mybits, 1);
  u32 w  = (pb << 16) | mybits;          // even lane: (lo = d even, hi = d odd)
  int b = bt / T_, t = bt % T_;
  if (!(lane & 1)) {
    int c32 = lane >> 1;                 // u32 col 0..31  (d = 2c, 2c+1)
    int kl = t & 63, tile = t >> 6;
    int sp = (c32 >> 2) ^ (kl & 7);      // pre-swizzled segment
    k_ws[(((size_t)(b * N_KV + kvh) * NTILES + tile)) * TILE_U32 + kl * 32 + sp * 4 + (c32 & 3)] = w;
  }
}

// ---------------- Kernel 1b: V -> bf16, transposed [d][key] tiles, pre-swizzled ----------
// ws layout: [b][kvh][tile][d(64)][seg_phys(8) of 16B]; u32 col c <-> keys (2c,2c+1);
// seg_phys = (c>>2) ^ (d&7)
__global__ __launch_bounds__(256) void prep_v_kernel(
    const float* __restrict__ v_in, u32* __restrict__ v_ws)
{
  int blk  = blockIdx.x;                 // (b*N_KV+kvh)*NTILES + tile
  int tile = blk & (NTILES - 1);
  int bk   = blk >> 5;
  int kvh  = bk % N_KV, b = bk / N_KV;
  int t0   = tile * 64;
  int tid  = threadIdx.x;

  __shared__ u16 Tl[64][72];             // [d][key]

  #pragma unroll
  for (int it = 0; it < 4; ++it) {
    int idx = it * 256 + tid;            // 0..1023
    int kl = idx >> 4, dq = idx & 15;
    const float4 f = *(const float4*)&v_in[((size_t)(b * T_ + t0 + kl)) * (N_KV * HEAD_DIM) + kvh * HEAD_DIM + dq * 4];
    Tl[dq * 4 + 0][kl] = bf16_bits(f.x);
    Tl[dq * 4 + 1][kl] = bf16_bits(f.y);
    Tl[dq * 4 + 2][kl] = bf16_bits(f.z);
    Tl[dq * 4 + 3][kl] = bf16_bits(f.w);
  }
  __syncthreads();

  u32* outb = v_ws + (size_t)blk * TILE_U32;
  #pragma unroll
  for (int it = 0; it < 8; ++it) {
    int o = it * 256 + tid;              // 0..2047
    int d = o >> 5, c = o & 31;
    u32 w = ((u32)Tl[d][2 * c + 1] << 16) | Tl[d][2 * c];
    int sp = (c >> 2) ^ (d & 7);
    outb[d * 32 + sp * 4 + (c & 3)] = w;
  }
}

// ---------------- Kernel 2: fused MFMA flash attention, 2-phase pipelined ----------------
__global__ __launch_bounds__(256) void attn_kernel(
    const float* __restrict__ q_in, const float* __restrict__ q_w,
    const int* __restrict__ pos_ids,
    const u32* __restrict__ kws, const u32* __restrict__ vws,
    float* __restrict__ out)
{
  const int blk = blockIdx.x;
  const int u   = blk & 31, v = blk >> 5;          // v in 0..49
  const int qt  = (u + v) & 31;                    // spread tile-counts across CUs
  const int h   = v % N_HEADS;
  const int b   = v / N_HEADS;
  const int qb  = qt * QB;
  const int kvh = h / (N_HEADS / N_KV);
  const int tid = threadIdx.x, wid = tid >> 6, lane = tid & 63;
  const int l15 = lane & 15, g = lane >> 4;
  const int qrow0 = wid * 16;

  __shared__ u32 Ks[2][TILE_U32];        // K tile, rows=key, XOR-swizzled segs (8 KB each)
  __shared__ u32 Vt[2][TILE_U32];        // V^T tile, rows=d, XOR-swizzled segs
  __shared__ u32 Pq[4][16][36];          // per-wave: Q rows (init), then P rows

  // ---- Q staging: RMSNorm + RoPE; scale = 0.125 * log2(e) (exp2 softmax domain) ----
  {
    const float base = powf(10000.f, -(float)(lane & 31) * (1.f / 32.f));
    for (int r = 0; r < 16; ++r) {
      int t = qb + qrow0 + r;
      float x = q_in[((size_t)(b * T_ + t)) * (N_HEADS * HEAD_DIM) + h * HEAD_DIM + lane];
      float ss = x * x;
      #pragma unroll
      for (int off = 32; off; off >>= 1) ss += __shfl_xor(ss, off);
      float y = q_w[lane] * x * rsqrtf(ss * (1.f / 64.f) + 1e-6f);
      float ang = (float)pos_ids[b * T_ + t] * base;
      float c, s;
      sincosf(ang, &s, &c);
      float part = __shfl_xor(y, 32);
      float rv = ((lane < 32) ? (y * c - part * s) : (y * c + part * s)) * 0.18033688f;
      u16 mybits = bf16_bits(rv);
      u32 pb = (u32)(u16)__shfl_xor((int)mybits, 1);
      u32 w  = (pb << 16) | mybits;
      if (!(lane & 1)) Pq[wid][r][lane >> 1] = w;
    }
  }

  bf16x8 qf[2];
  #pragma unroll
  for (int ks = 0; ks < 2; ++ks)
    qf[ks] = *(const bf16x8*)&Pq[wid][l15][16 * ks + 4 * g];

  float m_reg = -INFINITY, l_reg = 0.f;
  f32x4 acc_o[4];
  #pragma unroll
  for (int mt = 0; mt < 4; ++mt) acc_o[mt] = (f32x4)(0.f);

  const int q_abs = qb + qrow0 + l15;

  // tile list: {0,1} U [max(2, qt-16), qt]  (closed form, no divergent skips)
  const int nt    = (qt <= 18) ? (qt + 1) : 19;
  const int shift = qt - 18;                       // only used when qt > 18

  const size_t kvbase = ((size_t)(b * N_KV + kvh)) * NTILES * TILE_U32;
  const u32* kb = kws + kvbase;
  const u32* vb = vws + kvbase;

  // ---- prologue: stage tile 0 into buf 0 ----
  #pragma unroll
  for (int j = 0; j < 4; ++j) {
    int ci = (wid << 2) | j;                       // wave-uniform chunk id 0..15
    if (ci < 8) gload16(kb + ci * 256 + lane * 4, &Ks[0][ci * 256]);
    else        gload16(vb + (ci - 8) * 256 + lane * 4, &Vt[0][(ci - 8) * 256]);
  }
  __syncthreads();

  int buf = 0;
  for (int i = 0; i < nt; ++i) {
    // ---- issue next tile's staging (hidden under this tile's compute) ----
    if (i + 1 < nt) {
      int tn = (qt <= 18 || i + 1 < 2) ? (i + 1) : (i + 1 + shift);
      const u32* kt = kb + (size_t)tn * TILE_U32;
      const u32* vt = vb + (size_t)tn * TILE_U32;
      #pragma unroll
      for (int j = 0; j < 4; ++j) {
        int ci = (wid << 2) | j;
        if (ci < 8) gload16(kt + ci * 256 + lane * 4, &Ks[buf ^ 1][ci * 256]);
        else        gload16(vt + (ci - 8) * 256 + lane * 4, &Vt[buf ^ 1][(ci - 8) * 256]);
      }
    }
    const int k0 = ((qt <= 18 || i < 2) ? i : i + shift) << 6;

    // ---- S^T = K·Q^T (C: col=l15=q, row=key 16mt+4g+rg) ----
    f32x4 accs[4];
    #pragma unroll
    for (int mt = 0; mt < 4; ++mt) accs[mt] = (f32x4)(0.f);
    #pragma unroll
    for (int ks = 0; ks < 2; ++ks) {
      #pragma unroll
      for (int mt = 0; mt < 4; ++mt) {
        bf16x8 kf = *(const bf16x8*)&Ks[buf][(16 * mt + l15) * 32 + (((4 * ks + g) ^ (l15 & 7)) << 2)];
        accs[mt] = __builtin_amdgcn_mfma_f32_16x16x32_bf16(kf, qf[ks], accs[mt], 0, 0, 0);
      }
    }

    // ---- mask + online softmax (exp2 domain), in place ----
    float tmax = -INFINITY;
    #pragma unroll
    for (int mt = 0; mt < 4; ++mt)
      #pragma unroll
      for (int rg = 0; rg < 4; ++rg) {
        int key = k0 + 16 * mt + 4 * g + rg;
        bool ok = (key <= q_abs) && ((key >= q_abs - (WINDOW - 1)) || (key < N_META));
        float sv = ok ? accs[mt][rg] : -INFINITY;
        accs[mt][rg] = sv;
        tmax = fmaxf(tmax, sv);
      }
    tmax = fmaxf(tmax, __shfl_xor(tmax, 16));
    tmax = fmaxf(tmax, __shfl_xor(tmax, 32));
    float mn  = fmaxf(m_reg, tmax);
    float scl = exp2f(m_reg - mn);
    m_reg = mn;
    float rsum = 0.f;
    #pragma unroll
    for (int mt = 0; mt < 4; ++mt)
      #pragma unroll
      for (int rg = 0; rg < 4; ++rg) {
        float pi = exp2f(accs[mt][rg] - mn);
        accs[mt][rg] = pi;
        rsum += pi;
      }
    rsum += __shfl_xor(rsum, 16);
    rsum += __shfl_xor(rsum, 32);
    l_reg = l_reg * scl + rsum;

    // ---- pack P -> wave-private LDS rows ----
    #pragma unroll
    for (int mt = 0; mt < 4; ++mt)
      #pragma unroll
      for (int c2 = 0; c2 < 2; ++c2) {
        u32 w = ((u32)bf16_bits(accs[mt][2 * c2 + 1]) << 16) | bf16_bits(accs[mt][2 * c2]);
        Pq[wid][l15][8 * mt + 2 * g + c2] = w;
      }

    // ---- rescale O (rows are q' = 4g + rg) ----
    float scl4[4];
    #pragma unroll
    for (int rg = 0; rg < 4; ++rg) scl4[rg] = __shfl(scl, 4 * g + rg);
    #pragma unroll
    for (int mt2 = 0; mt2 < 4; ++mt2)
      #pragma unroll
      for (int rg = 0; rg < 4; ++rg) acc_o[mt2][rg] *= scl4[rg];

    // ---- O += P·V ----
    #pragma unroll
    for (int ks2 = 0; ks2 < 2; ++ks2) {
      bf16x8 af = *(const bf16x8*)&Pq[wid][l15][16 * ks2 + 4 * g];
      #pragma unroll
      for (int mt2 = 0; mt2 < 4; ++mt2) {
        bf16x8 vf = *(const bf16x8*)&Vt[buf][(16 * mt2 + l15) * 32 + (((4 * ks2 + g) ^ (l15 & 7)) << 2)];
        acc_o[mt2] = __builtin_amdgcn_mfma_f32_16x16x32_bf16(af, vf, acc_o[mt2], 0, 0, 0);
      }
    }

    __syncthreads();     // drains vmcnt (next tile landed) + all waves done with buf
    buf ^= 1;
  }

  // ---- epilogue ----
  float l4[4];
  #pragma unroll
  for (int rg = 0; rg < 4; ++rg) l4[rg] = __shfl(l_reg, 4 * g + rg);
  #pragma unroll
  for (int mt2 = 0; mt2 < 4; ++mt2)
    #pragma unroll
    for (int rg = 0; rg < 4; ++rg) {
      int t = qb + qrow0 + 4 * g + rg;
      out[((size_t)(b * T_ + t)) * (N_HEADS * HEAD_DIM) + h * HEAD_DIM + 16 * mt2 + l15] =
          acc_o[mt2][rg] / l4[rg];
    }
}

extern "C" void kernel_launch(void* const* d_in, const int* in_sizes, int n_in,
                              void* d_out, int out_size, void* d_ws, size_t ws_size,
                              hipStream_t stream) {
  const float* q   = (const float*)d_in[0];
  const float* k   = (const float*)d_in[1];
  const float* v   = (const float*)d_in[2];
  const float* qw  = (const float*)d_in[3];
  const float* kw  = (const float*)d_in[4];
  const int*   pos = (const int*)d_in[5];

  u32* kp = (u32*)d_ws;                                    // 320 tiles * 8KB = 2.62 MB
  u32* vp = kp + (size_t)B_ * N_KV * NTILES * TILE_U32;    // 2.62 MB
  float* outp = (float*)d_out;

  prep_k_kernel<<<5120, 256, 0, stream>>>(k, kw, pos, kp);
  prep_v_kernel<<<B_ * N_KV * NTILES, 256, 0, stream>>>(v, vp);
  attn_kernel<<<1600, 256, 0, stream>>>(q, qw, pos, kp, vp, outp);
}

// Round 5
// 91.587 us; speedup vs baseline: 23.1281x; 1.4472x over previous
//
#include <hip/hip_runtime.h>
#include <cmath>

typedef float  f32x4  __attribute__((ext_vector_type(4)));
typedef __bf16 bf16x8 __attribute__((ext_vector_type(8)));
typedef __bf16 bf16x4 __attribute__((ext_vector_type(4)));
typedef unsigned int u32x4 __attribute__((ext_vector_type(4)));
typedef unsigned int   u32;
typedef unsigned short u16;

#define HEAD_DIM 64
#define N_HEADS  25
#define N_KV     5
#define WINDOW   1024
#define N_META   128
#define B_       2
#define T_       2048
#define QB       64
#define NTILES   (T_ / 64)
#define TILE_U32 2048               // 64 rows x 32 u32 (8 KB)

static __device__ __forceinline__ u16 bf16_bits(float f) {
  __bf16 h = (__bf16)f;
  return __builtin_bit_cast(u16, h);
}
static __device__ __forceinline__ u32 pack2(float lo, float hi) {
  return ((u32)bf16_bits(hi) << 16) | bf16_bits(lo);
}
static __device__ __forceinline__ void gload16(const u32* g, u32* l) {
  __builtin_amdgcn_global_load_lds((const __attribute__((address_space(1))) u32*)g,
                                   (__attribute__((address_space(3))) u32*)l, 16, 0, 0);
}

// ---------------- Kernel 1: K RMSNorm+RoPE -> bf16 tiles, seg-XOR pre-swizzled ----------
// [b][kvh][tile][key(64)][seg_phys(8) x 4 u32]; seg_phys = seg_log ^ (key&7)
__global__ __launch_bounds__(256) void prep_k_kernel(
    const float* __restrict__ k_in, const float* __restrict__ k_w,
    const int* __restrict__ pos_ids, u32* __restrict__ k_ws)
{
  int gw   = (blockIdx.x * blockDim.x + threadIdx.x) >> 6;
  int lane = threadIdx.x & 63;
  if (gw >= B_ * T_ * N_KV) return;
  int kvh = gw % N_KV;
  int bt  = gw / N_KV;

  float x = k_in[(size_t)bt * (N_KV * HEAD_DIM) + kvh * HEAD_DIM + lane];
  float ss = x * x;
  #pragma unroll
  for (int off = 32; off; off >>= 1) ss += __shfl_xor(ss, off);
  float y = k_w[lane] * x * rsqrtf(ss * (1.f / 64.f) + 1e-6f);

  int   pos = pos_ids[bt];
  float ang = (float)pos * powf(10000.f, -(float)(lane & 31) * (1.f / 32.f));
  float c, s;
  sincosf(ang, &s, &c);
  float part = __shfl_xor(y, 32);
  float r = (lane < 32) ? (y * c - part * s) : (y * c + part * s);

  u16 mybits = bf16_bits(r);
  u32 pb = (u32)(u16)__shfl_xor((int)mybits, 1);
  u32 w  = (pb << 16) | mybits;
  int b = bt / T_, t = bt % T_;
  if (!(lane & 1)) {
    int c32 = lane >> 1;
    int kl = t & 63, tile = t >> 6;
    int sp = (c32 >> 2) ^ (kl & 7);
    k_ws[(((size_t)(b * N_KV + kvh) * NTILES + tile)) * TILE_U32 + kl * 32 + sp * 4 + (c32 & 3)] = w;
  }
}

// ---------------- Kernel 1b: V -> bf16 V^T tiles, b64-pair pre-swizzled ----------------
// [b][kvh][tile][d(64)][u32 32]; log u32 col c holds keys (2c,2c+1);
// stored at pair p = (c>>1)^(d&15), slot c&1  -> phys idx d*32 + 2p + (c&1)
__global__ __launch_bounds__(256) void prep_v_kernel(
    const float* __restrict__ v_in, u32* __restrict__ v_ws)
{
  int blk  = blockIdx.x;
  int tile = blk & (NTILES - 1);
  int bk   = blk >> 5;
  int kvh  = bk % N_KV, b = bk / N_KV;
  int t0   = tile * 64;
  int tid  = threadIdx.x;

  __shared__ u16 Tl[64][72];             // [d][key]

  #pragma unroll
  for (int it = 0; it < 4; ++it) {
    int idx = it * 256 + tid;
    int kl = idx >> 4, dq = idx & 15;
    const float4 f = *(const float4*)&v_in[((size_t)(b * T_ + t0 + kl)) * (N_KV * HEAD_DIM) + kvh * HEAD_DIM + dq * 4];
    Tl[dq * 4 + 0][kl] = bf16_bits(f.x);
    Tl[dq * 4 + 1][kl] = bf16_bits(f.y);
    Tl[dq * 4 + 2][kl] = bf16_bits(f.z);
    Tl[dq * 4 + 3][kl] = bf16_bits(f.w);
  }
  __syncthreads();

  u32* outb = v_ws + (size_t)blk * TILE_U32;
  #pragma unroll
  for (int it = 0; it < 8; ++it) {
    int o = it * 256 + tid;
    int d = o >> 5, c = o & 31;
    u32 w = ((u32)Tl[d][2 * c + 1] << 16) | Tl[d][2 * c];
    int p = (c >> 1) ^ (d & 15);
    outb[d * 32 + p * 2 + (c & 1)] = w;
  }
}

// ---------------- Kernel 2: fused MFMA flash attention ----------------
__global__ __launch_bounds__(256, 4) void attn_kernel(
    const float* __restrict__ q_in, const float* __restrict__ q_w,
    const int* __restrict__ pos_ids,
    const u32* __restrict__ kws, const u32* __restrict__ vws,
    float* __restrict__ out)
{
  const int blk = blockIdx.x;
  const int r   = blk / 50, v = blk % 50;          // heavy-first: qt descending
  const int qt  = 31 - r;
  const int h   = v % N_HEADS;
  const int b   = v / N_HEADS;
  const int qb  = qt * QB;
  const int kvh = h / (N_HEADS / N_KV);
  const int tid = threadIdx.x, wid = tid >> 6, lane = tid & 63;
  const int l15 = lane & 15, g = lane >> 4;
  const int qrow0 = wid * 16;

  __shared__ u32 Ks[2 * TILE_U32];       // K tiles (buf1 doubles as Q staging pre-loop)
  __shared__ u32 Vt[2 * TILE_U32];       // V^T tiles

  const int nt    = (qt <= 18) ? (qt + 1) : 19;
  const int shift = qt - 18;

  const size_t kvbase = ((size_t)(b * N_KV + kvh)) * NTILES * TILE_U32;
  const u32* kb = kws + kvbase;
  const u32* vb = vws + kvbase;

  // ---- issue tile-0 staging first (hides under Q-staging compute) ----
  #pragma unroll
  for (int j = 0; j < 4; ++j) {
    int ci = (wid << 2) | j;
    if (ci < 8) gload16(kb + ci * 256 + lane * 4, &Ks[ci * 256]);
    else        gload16(vb + (ci - 8) * 256 + lane * 4, &Vt[(ci - 8) * 256]);
  }

  // ---- Q staging into Ks buf1: RMSNorm + RoPE; scale = 0.125*log2(e) ----
  {
    const float base = powf(10000.f, -(float)(lane & 31) * (1.f / 32.f));
    for (int rr = 0; rr < 16; ++rr) {
      int t = qb + qrow0 + rr;
      float x = q_in[((size_t)(b * T_ + t)) * (N_HEADS * HEAD_DIM) + h * HEAD_DIM + lane];
      float ss = x * x;
      #pragma unroll
      for (int off = 32; off; off >>= 1) ss += __shfl_xor(ss, off);
      float y = q_w[lane] * x * rsqrtf(ss * (1.f / 64.f) + 1e-6f);
      float ang = (float)pos_ids[b * T_ + t] * base;
      float c, s;
      sincosf(ang, &s, &c);
      float part = __shfl_xor(y, 32);
      float rv = ((lane < 32) ? (y * c - part * s) : (y * c + part * s)) * 0.18033688f;
      u16 mybits = bf16_bits(rv);
      u32 pb = (u32)(u16)__shfl_xor((int)mybits, 1);
      if (!(lane & 1)) Ks[TILE_U32 + (qrow0 + rr) * 32 + (lane >> 1)] = (pb << 16) | mybits;
    }
  }
  __syncthreads();                       // tile0 loads drained + Q rows visible

  bf16x8 qf[2];
  #pragma unroll
  for (int ks = 0; ks < 2; ++ks)
    qf[ks] = *(const bf16x8*)&Ks[TILE_U32 + (qrow0 + l15) * 32 + 16 * ks + 4 * g];
  __syncthreads();                       // all qf reads done before buf1 is overwritten

  float m_reg = -INFINITY, l_reg = 0.f;
  f32x4 acc_o[4];
  #pragma unroll
  for (int mt = 0; mt < 4; ++mt) acc_o[mt] = (f32x4)(0.f);

  const int q_abs = qb + qrow0 + l15;

  int buf = 0;
  for (int i = 0; i < nt; ++i) {
    // ---- prefetch next tile into buf^1 ----
    if (i + 1 < nt) {
      int tn = (qt <= 18 || i + 1 < 2) ? (i + 1) : (i + 1 + shift);
      const u32* kt = kb + (size_t)tn * TILE_U32;
      const u32* vt = vb + (size_t)tn * TILE_U32;
      u32* kd = &Ks[(buf ^ 1) * TILE_U32];
      u32* vd = &Vt[(buf ^ 1) * TILE_U32];
      #pragma unroll
      for (int j = 0; j < 4; ++j) {
        int ci = (wid << 2) | j;
        if (ci < 8) gload16(kt + ci * 256 + lane * 4, kd + ci * 256);
        else        gload16(vt + (ci - 8) * 256 + lane * 4, vd + (ci - 8) * 256);
      }
    }
    const int k0 = ((qt <= 18 || i < 2) ? i : i + shift) << 6;

    // ---- S^T = K·Q^T (C: col=l15=q, row=key 16mt+4g+rg) ----
    f32x4 accs[4];
    #pragma unroll
    for (int mt = 0; mt < 4; ++mt) accs[mt] = (f32x4)(0.f);
    #pragma unroll
    for (int ks = 0; ks < 2; ++ks) {
      #pragma unroll
      for (int mt = 0; mt < 4; ++mt) {
        bf16x8 kf = *(const bf16x8*)&Ks[buf * TILE_U32 + (16 * mt + l15) * 32 + (((4 * ks + g) ^ (l15 & 7)) << 2)];
        accs[mt] = __builtin_amdgcn_mfma_f32_16x16x32_bf16(kf, qf[ks], accs[mt], 0, 0, 0);
      }
    }

    // ---- mask only on boundary tiles (diagonal; window-entry when qt>=18) ----
    const bool do_mask = (i == nt - 1) || (qt >= 18 && i == 2);
    float tmax = -INFINITY;
    if (do_mask) {
      #pragma unroll
      for (int mt = 0; mt < 4; ++mt)
        #pragma unroll
        for (int rg = 0; rg < 4; ++rg) {
          int key = k0 + 16 * mt + 4 * g + rg;
          bool ok = (key <= q_abs) && ((key >= q_abs - (WINDOW - 1)) || (key < N_META));
          float sv = ok ? accs[mt][rg] : -INFINITY;
          accs[mt][rg] = sv;
          tmax = fmaxf(tmax, sv);
        }
    } else {
      #pragma unroll
      for (int mt = 0; mt < 4; ++mt)
        #pragma unroll
        for (int rg = 0; rg < 4; ++rg) tmax = fmaxf(tmax, accs[mt][rg]);
    }
    tmax = fmaxf(tmax, __shfl_xor(tmax, 16));
    tmax = fmaxf(tmax, __shfl_xor(tmax, 32));

    // ---- online softmax (exp2 domain) with defer-skip ----
    float mn = m_reg;
    if (!__all(tmax <= m_reg)) {
      mn = fmaxf(m_reg, tmax);
      float scl = exp2f(m_reg - mn);
      m_reg = mn;
      l_reg *= scl;
      float scl4[4];
      #pragma unroll
      for (int rg = 0; rg < 4; ++rg) scl4[rg] = __shfl(scl, 4 * g + rg);
      #pragma unroll
      for (int mt2 = 0; mt2 < 4; ++mt2)
        #pragma unroll
        for (int rg = 0; rg < 4; ++rg) acc_o[mt2][rg] *= scl4[rg];
    }
    float rsum = 0.f;
    #pragma unroll
    for (int mt = 0; mt < 4; ++mt)
      #pragma unroll
      for (int rg = 0; rg < 4; ++rg) {
        float pi = exp2f(accs[mt][rg] - mn);
        accs[mt][rg] = pi;
        rsum += pi;
      }
    rsum += __shfl_xor(rsum, 16);
    rsum += __shfl_xor(rsum, 32);
    l_reg += rsum;

    // ---- O += P·V, P in-register (permuted-K mfma; V read b64 in matching order) ----
    #pragma unroll
    for (int ks2 = 0; ks2 < 2; ++ks2) {
      const int m0 = 2 * ks2, m1 = 2 * ks2 + 1;
      u32x4 aw;
      aw.x = pack2(accs[m0][0], accs[m0][1]);
      aw.y = pack2(accs[m0][2], accs[m0][3]);
      aw.z = pack2(accs[m1][0], accs[m1][1]);
      aw.w = pack2(accs[m1][2], accs[m1][3]);
      bf16x8 af = __builtin_bit_cast(bf16x8, aw);
      #pragma unroll
      for (int mt2 = 0; mt2 < 4; ++mt2) {
        const u32* vrow = &Vt[buf * TILE_U32 + (16 * mt2 + l15) * 32];
        bf16x4 v0 = *(const bf16x4*)&vrow[2 * ((8 * ks2 + g) ^ l15)];
        bf16x4 v1 = *(const bf16x4*)&vrow[2 * ((8 * ks2 + 4 + g) ^ l15)];
        bf16x8 vf = __builtin_shufflevector(v0, v1, 0, 1, 2, 3, 4, 5, 6, 7);
        acc_o[mt2] = __builtin_amdgcn_mfma_f32_16x16x32_bf16(af, vf, acc_o[mt2], 0, 0, 0);
      }
    }

    __syncthreads();     // drains vmcnt (next tile landed) + all waves done with buf
    buf ^= 1;
  }

  // ---- epilogue: C rows are q' = 4g+rg, col d = 16mt2+l15 (coalesced stores) ----
  float l4[4];
  #pragma unroll
  for (int rg = 0; rg < 4; ++rg) l4[rg] = __shfl(l_reg, 4 * g + rg);
  #pragma unroll
  for (int mt2 = 0; mt2 < 4; ++mt2)
    #pragma unroll
    for (int rg = 0; rg < 4; ++rg) {
      int t = qb + qrow0 + 4 * g + rg;
      out[((size_t)(b * T_ + t)) * (N_HEADS * HEAD_DIM) + h * HEAD_DIM + 16 * mt2 + l15] =
          acc_o[mt2][rg] / l4[rg];
    }
}

extern "C" void kernel_launch(void* const* d_in, const int* in_sizes, int n_in,
                              void* d_out, int out_size, void* d_ws, size_t ws_size,
                              hipStream_t stream) {
  const float* q   = (const float*)d_in[0];
  const float* k   = (const float*)d_in[1];
  const float* v   = (const float*)d_in[2];
  const float* qw  = (const float*)d_in[3];
  const float* kw  = (const float*)d_in[4];
  const int*   pos = (const int*)d_in[5];

  u32* kp = (u32*)d_ws;                                    // 2.62 MB
  u32* vp = kp + (size_t)B_ * N_KV * NTILES * TILE_U32;    // 2.62 MB
  float* outp = (float*)d_out;

  prep_k_kernel<<<5120, 256, 0, stream>>>(k, kw, pos, kp);
  prep_v_kernel<<<B_ * N_KV * NTILES, 256, 0, stream>>>(v, vp);
  attn_kernel<<<1600, 256, 0, stream>>>(q, qw, pos, kp, vp, outp);
}

// Round 7
// 88.263 us; speedup vs baseline: 23.9990x; 1.0377x over previous
//
#include <hip/hip_runtime.h>
#include <cmath>

typedef float  f32x4  __attribute__((ext_vector_type(4)));
typedef __bf16 bf16x8 __attribute__((ext_vector_type(8)));
typedef unsigned int u32x4 __attribute__((ext_vector_type(4)));
typedef unsigned int   u32;
typedef unsigned short u16;

#define HEAD_DIM 64
#define N_HEADS  25
#define N_KV     5
#define WINDOW   1024
#define N_META   128
#define B_       2
#define T_       2048
#define QB       64
#define NTILES   (T_ / 64)
#define TILE_U32 2048               // 64 rows x 32 u32 (8 KB)

static __device__ __forceinline__ u16 bf16_bits(float f) {
  __bf16 h = (__bf16)f;
  return __builtin_bit_cast(u16, h);
}
static __device__ __forceinline__ u32 pack2(float lo, float hi) {
  return ((u32)bf16_bits(hi) << 16) | bf16_bits(lo);
}
static __device__ __forceinline__ void gload16(const u32* g, u32* l) {
  __builtin_amdgcn_global_load_lds((const __attribute__((address_space(1))) u32*)g,
                                   (__attribute__((address_space(3))) u32*)l, 16, 0, 0);
}

// ---------------- Kernel 1: K RMSNorm+RoPE -> bf16 tiles, seg-XOR pre-swizzled ----------
// [b][kvh][tile][key(64)][seg_phys(8) x 4 u32]; seg_phys = seg_log ^ (key&7)
__global__ __launch_bounds__(256) void prep_k_kernel(
    const float* __restrict__ k_in, const float* __restrict__ k_w,
    const int* __restrict__ pos_ids, u32* __restrict__ k_ws)
{
  int gw   = (blockIdx.x * blockDim.x + threadIdx.x) >> 6;
  int lane = threadIdx.x & 63;
  if (gw >= B_ * T_ * N_KV) return;
  int kvh = gw % N_KV;
  int bt  = gw / N_KV;

  float x = k_in[(size_t)bt * (N_KV * HEAD_DIM) + kvh * HEAD_DIM + lane];
  float ss = x * x;
  #pragma unroll
  for (int off = 32; off; off >>= 1) ss += __shfl_xor(ss, off);
  float y = k_w[lane] * x * rsqrtf(ss * (1.f / 64.f) + 1e-6f);

  int   pos = pos_ids[bt];
  float ang = (float)pos * powf(10000.f, -(float)(lane & 31) * (1.f / 32.f));
  float c, s;
  sincosf(ang, &s, &c);
  float part = __shfl_xor(y, 32);
  float r = (lane < 32) ? (y * c - part * s) : (y * c + part * s);

  u16 mybits = bf16_bits(r);
  u32 pb = (u32)(u16)__shfl_xor((int)mybits, 1);
  u32 w  = (pb << 16) | mybits;
  int b = bt / T_, t = bt % T_;
  if (!(lane & 1)) {
    int c32 = lane >> 1;
    int kl = t & 63, tile = t >> 6;
    int sp = (c32 >> 2) ^ (kl & 7);
    k_ws[(((size_t)(b * N_KV + kvh) * NTILES + tile)) * TILE_U32 + kl * 32 + sp * 4 + (c32 & 3)] = w;
  }
}

// ---------------- Kernel 1b: V -> bf16 V^T tiles, b128 K-group pre-swizzled ------------
// [b][kvh][tile][d(64)][32 u32]. Logical u32 col c holds keys (2c,2c+1). c = 16a+8b+2g+e
// stored at phys seg sp = (4a+g)^(d&7), slot 2b+e. Attn's b128 read at seg (4ks2+g)^(d&7)
// then yields keys {32ks2+4g+0..3, 32ks2+16+4g+0..3} = exactly the PV A-frag k-order.
__global__ __launch_bounds__(256) void prep_v_kernel(
    const float* __restrict__ v_in, u32* __restrict__ v_ws)
{
  int blk  = blockIdx.x;
  int tile = blk & (NTILES - 1);
  int bk   = blk >> 5;
  int kvh  = bk % N_KV, b = bk / N_KV;
  int t0   = tile * 64;
  int tid  = threadIdx.x;

  __shared__ u16 Tl[64][72];             // [d][key]

  #pragma unroll
  for (int it = 0; it < 4; ++it) {
    int idx = it * 256 + tid;
    int kl = idx >> 4, dq = idx & 15;
    const float4 f = *(const float4*)&v_in[((size_t)(b * T_ + t0 + kl)) * (N_KV * HEAD_DIM) + kvh * HEAD_DIM + dq * 4];
    Tl[dq * 4 + 0][kl] = bf16_bits(f.x);
    Tl[dq * 4 + 1][kl] = bf16_bits(f.y);
    Tl[dq * 4 + 2][kl] = bf16_bits(f.z);
    Tl[dq * 4 + 3][kl] = bf16_bits(f.w);
  }
  __syncthreads();

  u32* outb = v_ws + (size_t)blk * TILE_U32;
  #pragma unroll
  for (int it = 0; it < 8; ++it) {
    int o = it * 256 + tid;
    int d = o >> 5, c = o & 31;
    u32 w = ((u32)Tl[d][2 * c + 1] << 16) | Tl[d][2 * c];
    int a = c >> 4, bs = (c >> 3) & 1, gp = (c >> 1) & 3, e = c & 1;
    int sp = (4 * a + gp) ^ (d & 7);
    outb[d * 32 + sp * 4 + 2 * bs + e] = w;
  }
}

// ---------------- Kernel 2: fused MFMA flash attention ----------------
__global__ __launch_bounds__(256, 4) void attn_kernel(
    const float* __restrict__ q_in, const float* __restrict__ q_w,
    const int* __restrict__ pos_ids,
    const u32* __restrict__ kws, const u32* __restrict__ vws,
    float* __restrict__ out)
{
  const int blk = blockIdx.x;
  const int r   = blk / 50, v = blk % 50;          // heavy-first: qt descending
  const int qt  = 31 - r;
  const int h   = v % N_HEADS;
  const int b   = v / N_HEADS;
  const int qb  = qt * QB;
  const int kvh = h / (N_HEADS / N_KV);
  const int tid = threadIdx.x, wid = tid >> 6, lane = tid & 63;
  const int l15 = lane & 15, g = lane >> 4;
  const int qrow0 = wid * 16;

  __shared__ u32 Ks[2 * TILE_U32];       // K tiles (buf1 doubles as Q staging pre-loop)
  __shared__ u32 Vt[2 * TILE_U32];       // V^T tiles

  const int nt    = (qt <= 18) ? (qt + 1) : 19;
  const int shift = qt - 18;

  const size_t kvbase = ((size_t)(b * N_KV + kvh)) * NTILES * TILE_U32;
  const u32* kb = kws + kvbase;
  const u32* vb = vws + kvbase;

  // ---- issue tile-0 staging first (hides under Q-staging compute) ----
  #pragma unroll
  for (int j = 0; j < 4; ++j) {
    int ci = (wid << 2) | j;
    if (ci < 8) gload16(kb + ci * 256 + lane * 4, &Ks[ci * 256]);
    else        gload16(vb + (ci - 8) * 256 + lane * 4, &Vt[(ci - 8) * 256]);
  }

  // ---- Q staging into Ks buf1: RMSNorm + RoPE; scale = 0.125*log2(e) ----
  {
    const float base = powf(10000.f, -(float)(lane & 31) * (1.f / 32.f));
    for (int rr = 0; rr < 16; ++rr) {
      int t = qb + qrow0 + rr;
      float x = q_in[((size_t)(b * T_ + t)) * (N_HEADS * HEAD_DIM) + h * HEAD_DIM + lane];
      float ss = x * x;
      #pragma unroll
      for (int off = 32; off; off >>= 1) ss += __shfl_xor(ss, off);
      float y = q_w[lane] * x * rsqrtf(ss * (1.f / 64.f) + 1e-6f);
      float ang = (float)pos_ids[b * T_ + t] * base;
      float c, s;
      sincosf(ang, &s, &c);
      float part = __shfl_xor(y, 32);
      float rv = ((lane < 32) ? (y * c - part * s) : (y * c + part * s)) * 0.18033688f;
      u16 mybits = bf16_bits(rv);
      u32 pb = (u32)(u16)__shfl_xor((int)mybits, 1);
      if (!(lane & 1)) Ks[TILE_U32 + (qrow0 + rr) * 32 + (lane >> 1)] = (pb << 16) | mybits;
    }
  }
  __syncthreads();                       // tile0 loads drained + Q rows visible

  bf16x8 qf[2];
  #pragma unroll
  for (int ks = 0; ks < 2; ++ks)
    qf[ks] = *(const bf16x8*)&Ks[TILE_U32 + (qrow0 + l15) * 32 + 16 * ks + 4 * g];
  __syncthreads();                       // all qf reads done before buf1 is overwritten

  float m_reg = -INFINITY, l_reg = 0.f;
  f32x4 acc_o[4];
  #pragma unroll
  for (int mt = 0; mt < 4; ++mt) acc_o[mt] = (f32x4)(0.f);

  const int q_abs = qb + qrow0 + l15;

  int buf = 0;
  for (int i = 0; i < nt; ++i) {
    // ---- prefetch next tile into buf^1 ----
    if (i + 1 < nt) {
      int tn = (qt <= 18 || i + 1 < 2) ? (i + 1) : (i + 1 + shift);
      const u32* kt = kb + (size_t)tn * TILE_U32;
      const u32* vt = vb + (size_t)tn * TILE_U32;
      u32* kd = &Ks[(buf ^ 1) * TILE_U32];
      u32* vd = &Vt[(buf ^ 1) * TILE_U32];
      #pragma unroll
      for (int j = 0; j < 4; ++j) {
        int ci = (wid << 2) | j;
        if (ci < 8) gload16(kt + ci * 256 + lane * 4, kd + ci * 256);
        else        gload16(vt + (ci - 8) * 256 + lane * 4, vd + (ci - 8) * 256);
      }
    }
    const int k0 = ((qt <= 18 || i < 2) ? i : i + shift) << 6;

    // ---- S^T = K·Q^T (C: col=l15=q, row=key 16mt+4g+rg) ----
    f32x4 accs[4];
    #pragma unroll
    for (int mt = 0; mt < 4; ++mt) accs[mt] = (f32x4)(0.f);
    #pragma unroll
    for (int ks = 0; ks < 2; ++ks) {
      #pragma unroll
      for (int mt = 0; mt < 4; ++mt) {
        bf16x8 kf = *(const bf16x8*)&Ks[buf * TILE_U32 + (16 * mt + l15) * 32 + (((4 * ks + g) ^ (l15 & 7)) << 2)];
        accs[mt] = __builtin_amdgcn_mfma_f32_16x16x32_bf16(kf, qf[ks], accs[mt], 0, 0, 0);
      }
    }

    // ---- mask only on boundary tiles (diagonal; window-entry when qt>=18) ----
    const bool do_mask = (i == nt - 1) || (qt >= 18 && i == 2);
    float tmax = -INFINITY;
    if (do_mask) {
      #pragma unroll
      for (int mt = 0; mt < 4; ++mt)
        #pragma unroll
        for (int rg = 0; rg < 4; ++rg) {
          int key = k0 + 16 * mt + 4 * g + rg;
          bool ok = (key <= q_abs) && ((key >= q_abs - (WINDOW - 1)) || (key < N_META));
          float sv = ok ? accs[mt][rg] : -INFINITY;
          accs[mt][rg] = sv;
          tmax = fmaxf(tmax, sv);
        }
    } else {
      #pragma unroll
      for (int mt = 0; mt < 4; ++mt)
        #pragma unroll
        for (int rg = 0; rg < 4; ++rg) tmax = fmaxf(tmax, accs[mt][rg]);
    }
    tmax = fmaxf(tmax, __shfl_xor(tmax, 16));
    tmax = fmaxf(tmax, __shfl_xor(tmax, 32));

    // ---- online softmax (exp2 domain) with defer-skip ----
    float mn = m_reg;
    if (!__all(tmax <= m_reg)) {
      mn = fmaxf(m_reg, tmax);
      float scl = exp2f(m_reg - mn);
      m_reg = mn;
      l_reg *= scl;
      float scl4[4];
      #pragma unroll
      for (int rg = 0; rg < 4; ++rg) scl4[rg] = __shfl(scl, 4 * g + rg);
      #pragma unroll
      for (int mt2 = 0; mt2 < 4; ++mt2)
        #pragma unroll
        for (int rg = 0; rg < 4; ++rg) acc_o[mt2][rg] *= scl4[rg];
    }
    float rsum = 0.f;
    #pragma unroll
    for (int mt = 0; mt < 4; ++mt)
      #pragma unroll
      for (int rg = 0; rg < 4; ++rg) {
        float pi = exp2f(accs[mt][rg] - mn);
        accs[mt][rg] = pi;
        rsum += pi;
      }
    rsum += __shfl_xor(rsum, 16);
    rsum += __shfl_xor(rsum, 32);
    l_reg += rsum;

    // ---- O += P·V, P in-register (permuted-K mfma; V b128 in matching order) ----
    #pragma unroll
    for (int ks2 = 0; ks2 < 2; ++ks2) {
      const int m0 = 2 * ks2, m1 = 2 * ks2 + 1;
      u32x4 aw;
      aw.x = pack2(accs[m0][0], accs[m0][1]);
      aw.y = pack2(accs[m0][2], accs[m0][3]);
      aw.z = pack2(accs[m1][0], accs[m1][1]);
      aw.w = pack2(accs[m1][2], accs[m1][3]);
      bf16x8 af = __builtin_bit_cast(bf16x8, aw);
      #pragma unroll
      for (int mt2 = 0; mt2 < 4; ++mt2) {
        bf16x8 vf = *(const bf16x8*)&Vt[buf * TILE_U32 + (16 * mt2 + l15) * 32 + (((4 * ks2 + g) ^ (l15 & 7)) << 2)];
        acc_o[mt2] = __builtin_amdgcn_mfma_f32_16x16x32_bf16(af, vf, acc_o[mt2], 0, 0, 0);
      }
    }

    __syncthreads();     // drains vmcnt (next tile landed) + all waves done with buf
    buf ^= 1;
  }

  // ---- epilogue: C rows are q' = 4g+rg, col d = 16mt2+l15 (coalesced stores) ----
  float l4[4];
  #pragma unroll
  for (int rg = 0; rg < 4; ++rg) l4[rg] = __shfl(l_reg, 4 * g + rg);
  #pragma unroll
  for (int mt2 = 0; mt2 < 4; ++mt2)
    #pragma unroll
    for (int rg = 0; rg < 4; ++rg) {
      int t = qb + qrow0 + 4 * g + rg;
      out[((size_t)(b * T_ + t)) * (N_HEADS * HEAD_DIM) + h * HEAD_DIM + 16 * mt2 + l15] =
          acc_o[mt2][rg] / l4[rg];
    }
}

extern "C" void kernel_launch(void* const* d_in, const int* in_sizes, int n_in,
                              void* d_out, int out_size, void* d_ws, size_t ws_size,
                              hipStream_t stream) {
  const float* q   = (const float*)d_in[0];
  const float* k   = (const float*)d_in[1];
  const float* v   = (const float*)d_in[2];
  const float* qw  = (const float*)d_in[3];
  const float* kw  = (const float*)d_in[4];
  const int*   pos = (const int*)d_in[5];

  u32* kp = (u32*)d_ws;                                    // 2.62 MB
  u32* vp = kp + (size_t)B_ * N_KV * NTILES * TILE_U32;    // 2.62 MB
  float* outp = (float*)d_out;

  prep_k_kernel<<<5120, 256, 0, stream>>>(k, kw, pos, kp);
  prep_v_kernel<<<B_ * N_KV * NTILES, 256, 0, stream>>>(v, vp);
  attn_kernel<<<1600, 256, 0, stream>>>(q, qw, pos, kp, vp, outp);
}